// Round 5
// baseline (1039.284 us; speedup 1.0000x reference)
//
#include <hip/hip_runtime.h>
#include <hip/hip_bf16.h>

#define B_ 32
#define C_ 48
#define H_ 64
#define W_ 128
#define K_ 5
#define SLAB (C_*H_*W_)
#define RS 72                 // carry row stride (bf16) = 144B (16B-aligned)
#define ROWS 132              // W_+4 halo rows (H-pass uses first 68)
#define KB 10                 // K blocks: 5*64/32
#define WC (W_*C_)
#define HC (H_*C_)
#define CBUF (ROWS*RS)        // 9504 shorts per carry buffer (19008 B)

typedef __attribute__((ext_vector_type(8))) short short8;
typedef __attribute__((ext_vector_type(4))) float f32x4;

__device__ __forceinline__ unsigned short f2bf(float f) {
  union { float f; unsigned u; } v; v.f = f;
  unsigned r = v.u + 0x7fffu + ((v.u >> 16) & 1u);
  return (unsigned short)(r >> 16);
}

__device__ __forceinline__ unsigned pk2(float a, float b) {
  union { __hip_bfloat162 h; unsigned u; } z;
  z.h = __float22bfloat162_rn(float2{a, b});
  return z.u;
}

// Weights as MFMA A operand: A[m][k'], m = mt*16 + (lane&15),
// k' = kb*32 + q*8 + j -> tap k = k'>>6, in-chan i = k'&63 (zero-pad 48..63).
__device__ __forceinline__ void load_wA(const float* __restrict__ wgt,
                                        const float* __restrict__ bias,
                                        short8 A[3][KB], float bv[3][4],
                                        int l15, int q) {
#pragma unroll
  for (int mt = 0; mt < 3; ++mt) {
#pragma unroll
    for (int r = 0; r < 4; ++r) bv[mt][r] = bias[mt * 16 + 4 * q + r];
#pragma unroll
    for (int kb = 0; kb < KB; ++kb) {
      short8 f;
#pragma unroll
      for (int j = 0; j < 8; ++j) {
        int kp = kb * 32 + q * 8 + j, k = kp >> 6, i = kp & 63;
        f[j] = (i < C_) ? (short)f2bf(wgt[(mt * 16 + l15) * (C_ * K_) + i * K_ + k])
                        : (short)0;
      }
      A[mt][kb] = f;
    }
  }
}

// One recurrence step, SINGLE WAVE, NT n-tiles of 16 spatial rows.
// out = conv(carry) + inp + bias; carry(scw) <- out. No barriers: same-wave
// LDS ops are in-order, scr/scw are distinct (double buffer).
template<int NT>
__device__ __forceinline__ void do_step(const unsigned short* __restrict__ scr,
                                        unsigned short* __restrict__ scw,
                                        const short8 A[3][KB], const float bv[3][4],
                                        const float* __restrict__ inp, size_t lRS,
                                        float* __restrict__ outp,
                                        int l15, int q, int c0) {
  // issue all input loads up front; consumed only in per-group epilogues
  float4 xv[NT][3];
#pragma unroll
  for (int nt = 0; nt < NT; ++nt) {
    const float* p = inp + (size_t)(nt * 16 + l15) * lRS + c0;
#pragma unroll
    for (int mt = 0; mt < 3; ++mt) xv[nt][mt] = *(const float4*)(p + mt * 16);
  }
  __builtin_amdgcn_sched_barrier(0);   // pin loads above the MFMA region

#pragma unroll
  for (int g = 0; g < NT / 2; ++g) {
    f32x4 acc[2][3];
#pragma unroll
    for (int u = 0; u < 2; ++u)
#pragma unroll
      for (int mt = 0; mt < 3; ++mt)
        acc[u][mt] = (f32x4){bv[mt][0], bv[mt][1], bv[mt][2], bv[mt][3]};
#pragma unroll
    for (int kb = 0; kb < KB; ++kb) {
      short8 pf[2];
#pragma unroll
      for (int u = 0; u < 2; ++u)
        pf[u] = *(const short8*)(scr
                 + (size_t)((2 * g + u) * 16 + l15 + (kb >> 1)) * RS
                 + (kb & 1) * 32 + q * 8);
#pragma unroll
      for (int u = 0; u < 2; ++u)
#pragma unroll
        for (int mt = 0; mt < 3; ++mt)
          acc[u][mt] = __builtin_amdgcn_mfma_f32_16x16x32_bf16(A[mt][kb], pf[u],
                                                               acc[u][mt], 0, 0, 0);
    }
#pragma unroll
    for (int u = 0; u < 2; ++u) {
      const int row = (2 * g + u) * 16 + l15;
#pragma unroll
      for (int mt = 0; mt < 3; ++mt) {
        float4 v;
        v.x = acc[u][mt][0] + xv[2 * g + u][mt].x;
        v.y = acc[u][mt][1] + xv[2 * g + u][mt].y;
        v.z = acc[u][mt][2] + xv[2 * g + u][mt].z;
        v.w = acc[u][mt][3] + xv[2 * g + u][mt].w;
        *(float4*)(outp + (size_t)row * C_ + mt * 16 + c0) = v;
        uint2 pk; pk.x = pk2(v.x, v.y); pk.y = pk2(v.z, v.w);
        *(uint2*)(scw + (size_t)(row + 2) * RS + mt * 16 + c0) = pk;
      }
    }
  }
}

// Pass-initial: carry = inp, out = inp (no conv, no bias).
template<int NT>
__device__ __forceinline__ void init_step(unsigned short* __restrict__ scw,
                                          const float* __restrict__ inp, size_t lRS,
                                          float* __restrict__ outp,
                                          int l15, int q, int c0) {
#pragma unroll
  for (int nt = 0; nt < NT; ++nt) {
    const int row = nt * 16 + l15;
    const float* p = inp + (size_t)row * lRS + c0;
#pragma unroll
    for (int mt = 0; mt < 3; ++mt) {
      float4 v = *(const float4*)(p + mt * 16);
      *(float4*)(outp + (size_t)row * C_ + mt * 16 + c0) = v;
      uint2 pk; pk.x = pk2(v.x, v.y); pk.y = pk2(v.z, v.w);
      *(uint2*)(scw + (size_t)(row + 2) * RS + mt * 16 + c0) = pk;
    }
  }
}

// One wave per batch. 64-thread blocks, grid = 32. Zero barriers.
__global__ __launch_bounds__(64, 1) void scnn_mfma(
    float* ws,                       // xT [b][h][w][c]; then R/L [b][t][h][c] (alias)
    const float* __restrict__ dw, const float* __restrict__ db,
    const float* __restrict__ rw, const float* __restrict__ rb,
    const float* __restrict__ lw, const float* __restrict__ lb,
    float* __restrict__ DU)          // d_out: D/U slabs [b][h][w][c]
{
  __shared__ unsigned short sb[2 * CBUF];   // 38016 B, double-buffered carry
  const int lane = threadIdx.x;             // 0..63
  const int l15 = lane & 15, q = lane >> 4, c0 = 4 * q;
  const int b = blockIdx.x;
  float* xbuf = ws + (size_t)b * SLAB;      // consumed by DOWN before R overwrites
  float* rl   = ws + (size_t)b * SLAB;
  float* du   = DU + (size_t)b * SLAB;

  short8 A[3][KB];
  float bv[3][4];
  int p = 0;

  // ---------------- DOWN: d[h] = x[h] + convW(d[h-1]) ----------------
  load_wA(dw, db, A, bv, l15, q);
  { unsigned* z = (unsigned*)sb; for (int i = lane; i < CBUF; i += 64) z[i] = 0u; }
  init_step<8>(sb, xbuf, (size_t)C_, du, l15, q, c0);          // d0 -> buffer 0
  p = 0;
  for (int s = 1; s < H_; ++s) {
    do_step<8>(sb + (size_t)p * CBUF, sb + (size_t)(p ^ 1) * CBUF, A, bv,
               xbuf + (size_t)s * WC, (size_t)C_, du + (size_t)s * WC, l15, q, c0);
    p ^= 1;
  }

  // ---------------- UP (down weights; carry = D[63] persists) --------
  for (int s = 1; s < H_; ++s) {
    int ih = (s <= H_ - 2) ? (H_ - 2 - s) : (H_ - 1);
    do_step<8>(sb + (size_t)p * CBUF, sb + (size_t)(p ^ 1) * CBUF, A, bv,
               du + (size_t)ih * WC, (size_t)C_,
               du + (size_t)(H_ - 1 - s) * WC, l15, q, c0);
    p ^= 1;
  }

  // ---------------- RIGHT: r[t] = U[...,t] + convH(r[t-1]) -----------
  load_wA(rw, rb, A, bv, l15, q);
  { unsigned* z = (unsigned*)sb; for (int i = lane; i < CBUF; i += 64) z[i] = 0u; }
  p = 0;
  init_step<4>(sb, du, (size_t)WC, rl, l15, q, c0);            // r0 = U[...,0]
  for (int s = 1; s < W_; ++s) {
    do_step<4>(sb + (size_t)p * CBUF, sb + (size_t)(p ^ 1) * CBUF, A, bv,
               du + (size_t)s * C_, (size_t)WC, rl + (size_t)s * HC, l15, q, c0);
    p ^= 1;
  }

  // ---------------- LEFT (carry = R[127]; L[127]=R[127] in place) ----
  load_wA(lw, lb, A, bv, l15, q);
  for (int s = 1; s < W_; ++s) {
    do_step<4>(sb + (size_t)p * CBUF, sb + (size_t)(p ^ 1) * CBUF, A, bv,
               rl + (size_t)(W_ - 1 - s) * HC, (size_t)C_,
               rl + (size_t)(W_ - 1 - s) * HC, l15, q, c0);
    p ^= 1;
  }
}

// x [b][c][h][w] -> xT [b][h][w][c]
__global__ __launch_bounds__(256) void xpose_chw_hwc(const float* __restrict__ x,
                                                     float* __restrict__ xT) {
  __shared__ float t[C_ * 129];
  const int bh = blockIdx.x, b = bh >> 6, h = bh & 63;
  const float* src = x + (size_t)b * SLAB + (size_t)h * W_;
  float* dst = xT + (size_t)b * SLAB + (size_t)h * (W_ * C_);
  for (int i = threadIdx.x; i < C_ * W_; i += 256) {
    int c = i >> 7, w = i & 127;
    t[c * 129 + w] = src[(size_t)c * (H_ * W_) + w];
  }
  __syncthreads();
  for (int i = threadIdx.x; i < C_ * W_; i += 256) {
    int w = i / C_, c = i - w * C_;
    dst[i] = t[c * 129 + w];
  }
}

// L [b][w][h][c] -> out [b][c][h][w]
__global__ __launch_bounds__(256) void xpose_whc_chw(const float* __restrict__ L,
                                                     float* __restrict__ out) {
  __shared__ float t[W_ * 49];
  const int bh = blockIdx.x, b = bh >> 6, h = bh & 63;
  const float* src = L + (size_t)b * SLAB + (size_t)h * C_;
  float* dst = out + (size_t)b * SLAB + (size_t)h * W_;
  for (int i = threadIdx.x; i < W_ * C_; i += 256) {
    int w = i / C_, c = i - w * C_;
    t[w * 49 + c] = src[(size_t)w * (H_ * C_) + c];
  }
  __syncthreads();
  for (int i = threadIdx.x; i < C_ * W_; i += 256) {
    int c = i >> 7, w = i & 127;
    dst[(size_t)c * (H_ * W_) + w] = t[w * 49 + c];
  }
}

extern "C" void kernel_launch(void* const* d_in, const int* in_sizes, int n_in,
                              void* d_out, int out_size, void* d_ws, size_t ws_size,
                              hipStream_t stream) {
  const float* x  = (const float*)d_in[0];
  const float* dw = (const float*)d_in[1];
  const float* db = (const float*)d_in[2];
  const float* rw = (const float*)d_in[3];
  const float* rb = (const float*)d_in[4];
  const float* lw = (const float*)d_in[5];
  const float* lb = (const float*)d_in[6];
  float* DU = (float*)d_out;
  float* WS = (float*)d_ws;

  xpose_chw_hwc<<<B_ * H_, 256, 0, stream>>>(x, WS);
  scnn_mfma<<<B_, 64, 0, stream>>>(WS, dw, db, rw, rb, lw, lb, DU);
  xpose_whc_chw<<<B_ * H_, 256, 0, stream>>>(WS, DU);
}

// Round 6
// 559.652 us; speedup vs baseline: 1.8570x; 1.8570x over previous
//
#include <hip/hip_runtime.h>
#include <hip/hip_bf16.h>

#define B_ 32
#define C_ 48
#define H_ 64
#define W_ 128
#define K_ 5
#define SLAB (C_*H_*W_)
#define RS 56                 // carry row stride in bf16 (112 B, 16B-aligned)
#define ROWS 136              // 128 rows + halo (reads reach row+5=132); rows 130+ stay 0
#define CBUF (ROWS*RS)        // shorts per carry buffer (15232 B)
#define WC (W_*C_)
#define HC (H_*C_)
#define KBN 8                 // K' = 256 (k' = k*48 + i; 240 real, 16 zero-pad)

typedef __attribute__((ext_vector_type(8))) short short8;
typedef __attribute__((ext_vector_type(4))) float f32x4;

__device__ __forceinline__ void lbar() {
  asm volatile("s_waitcnt lgkmcnt(0)\n\ts_barrier" ::: "memory");
}

__device__ __forceinline__ unsigned short f2bf(float f) {
  union { float f; unsigned u; } v; v.f = f;
  unsigned r = v.u + 0x7fffu + ((v.u >> 16) & 1u);
  return (unsigned short)(r >> 16);
}

__device__ __forceinline__ unsigned pk2(float a, float b) {
  union { __hip_bfloat162 h; unsigned u; } z;
  z.h = __float22bfloat162_rn(float2{a, b});
  return z.u;
}

// Weights as MFMA A operand. A[m][k'], m = (mt0+m)*16 + l15,
// k' = kb*32 + q8 + j; decode k = k'/48, i = k'%48; k' >= 240 -> 0.
// (48 % 8 == 0 so an aligned 8-block never crosses a tap boundary.)
template<int NM>
__device__ __forceinline__ void load_wA(const float* __restrict__ wgt,
                                        const float* __restrict__ bias,
                                        short8 A[NM][KBN], f32x4 bv[NM],
                                        int mt0, int l15, int q8, int c0) {
#pragma unroll
  for (int m = 0; m < NM; ++m) {
#pragma unroll
    for (int r = 0; r < 4; ++r) bv[m][r] = bias[(mt0 + m) * 16 + c0 + r];
#pragma unroll
    for (int kb = 0; kb < KBN; ++kb) {
      short8 f;
#pragma unroll
      for (int j = 0; j < 8; ++j) {
        int kp = kb * 32 + q8 + j;
        int k = kp / 48, i = kp - 48 * k;
        f[j] = (kp < 240)
             ? (short)f2bf(wgt[((mt0 + m) * 16 + l15) * (C_ * K_) + i * K_ + k])
             : (short)0;
      }
      A[m][kb] = f;
    }
  }
}

// One recurrence step for one wave: NM output-channel tiles, one 16-row n-tile.
// out = conv(carry[scr]) + inp + bias; carry[scw] <- out. One light barrier.
template<int NM>
__device__ __forceinline__ void stepN(const unsigned short* __restrict__ scr,
                                      unsigned short* __restrict__ scw,
                                      const short8 A[][KBN], const f32x4 bv[],
                                      const int off_r[KBN],
                                      const float* __restrict__ inp, size_t lRS,
                                      float* __restrict__ outp,
                                      int rowbase, int chb, int l15) {
  const int row = rowbase + l15;
  float4 xv[NM];
  {
    const float* ip = inp + (size_t)row * lRS + chb;
#pragma unroll
    for (int m = 0; m < NM; ++m) xv[m] = *(const float4*)(ip + m * 16);
  }
  __builtin_amdgcn_sched_barrier(0);   // keep input loads issued up front

  f32x4 acc[NM];
#pragma unroll
  for (int m = 0; m < NM; ++m) acc[m] = bv[m];

  const unsigned short* bp = scr + (size_t)rowbase * RS;
#pragma unroll
  for (int kb = 0; kb < KBN; ++kb) {
    short8 pf = *(const short8*)(bp + off_r[kb]);
#pragma unroll
    for (int m = 0; m < NM; ++m)
      acc[m] = __builtin_amdgcn_mfma_f32_16x16x32_bf16(A[m][kb], pf, acc[m], 0, 0, 0);
  }

  float* op = outp + (size_t)row * C_ + chb;
  unsigned short* wp = scw + (size_t)(row + 2) * RS + chb;
#pragma unroll
  for (int m = 0; m < NM; ++m) {
    float4 v;
    v.x = acc[m][0] + xv[m].x; v.y = acc[m][1] + xv[m].y;
    v.z = acc[m][2] + xv[m].z; v.w = acc[m][3] + xv[m].w;
    *(float4*)(op + m * 16) = v;
    uint2 pk; pk.x = pk2(v.x, v.y); pk.y = pk2(v.z, v.w);
    *(uint2*)(wp + m * 16) = pk;
  }
  lbar();
}

// Pass-initial: carry = inp, out = inp.
template<int NM>
__device__ __forceinline__ void initN(unsigned short* __restrict__ scw,
                                      const float* __restrict__ inp, size_t lRS,
                                      float* __restrict__ outp,
                                      int rowbase, int chb, int l15) {
  const int row = rowbase + l15;
  const float* ip = inp + (size_t)row * lRS + chb;
  float* op = outp + (size_t)row * C_ + chb;
  unsigned short* wp = scw + (size_t)(row + 2) * RS + chb;
#pragma unroll
  for (int m = 0; m < NM; ++m) {
    float4 v = *(const float4*)(ip + m * 16);
    *(float4*)(op + m * 16) = v;
    uint2 pk; pk.x = pk2(v.x, v.y); pk.y = pk2(v.z, v.w);
    *(uint2*)(wp + m * 16) = pk;
  }
  lbar();
}

__device__ __forceinline__ void zero_carry(unsigned short* sb, int tid) {
  unsigned* z = (unsigned*)sb;
  for (int i = tid; i < CBUF; i += 512) z[i] = 0u;   // 2*CBUF shorts = CBUF words
}

// RIGHT + LEFT for one wave group (NM channel tiles starting at mt0).
// Branch-divergent across waves but barrier sequence is identical.
template<int NM>
__device__ void hseq(unsigned short* sb, int mt0,
                     const float* __restrict__ rw, const float* __restrict__ rb,
                     const float* __restrict__ lw, const float* __restrict__ lb,
                     const float* __restrict__ du, float* __restrict__ rl,
                     int nt, int l15, int q8, int c0, const int off_r[KBN], int tid) {
  short8 A[NM][KBN];
  f32x4 bv[NM];
  zero_carry(sb, tid);
  __syncthreads();
  load_wA<NM>(rw, rb, A, bv, mt0, l15, q8, c0);
  const int rb16 = nt * 16, chb = mt0 * 16 + c0;
  int p = 0;
  // RIGHT: r[t] = U[...,t] + convH(r[t-1]); r0 = U[...,0]
  initN<NM>(sb, du, (size_t)WC, rl, rb16, chb, l15);
  for (int s = 1; s < W_; ++s) {
    stepN<NM>(sb + (size_t)p * CBUF, sb + (size_t)(p ^ 1) * CBUF, A, bv, off_r,
              du + (size_t)s * C_, (size_t)WC, rl + (size_t)s * HC, rb16, chb, l15);
    p ^= 1;
  }
  // LEFT: carry = R[127] (in LDS); L[127] = R[127] already in place in rl.
  load_wA<NM>(lw, lb, A, bv, mt0, l15, q8, c0);
  for (int s = 1; s < W_; ++s) {
    stepN<NM>(sb + (size_t)p * CBUF, sb + (size_t)(p ^ 1) * CBUF, A, bv, off_r,
              rl + (size_t)(W_ - 1 - s) * HC, (size_t)C_,
              rl + (size_t)(W_ - 1 - s) * HC, rb16, chb, l15);
    p ^= 1;
  }
}

// 8 waves (512 thr) per batch, 2 waves/SIMD. W passes: wave = n-tile (8x16=128).
// H passes: waves 0-3 -> (nt=wid, mt{0,1}); waves 4-7 -> (nt=wid-4, mt{2}).
__global__ __launch_bounds__(512, 2) void scnn_mfma(
    float* ws,                       // xT [b][h][w][c]; then R/L [b][t][h][c] (alias)
    const float* __restrict__ dw, const float* __restrict__ db,
    const float* __restrict__ rw, const float* __restrict__ rb,
    const float* __restrict__ lw, const float* __restrict__ lb,
    float* __restrict__ DU)          // d_out: D/U slabs [b][h][w][c]
{
  __shared__ unsigned short sb[2 * CBUF];   // 30464 B
  const int tid = threadIdx.x, lane = tid & 63, wid = tid >> 6;
  const int l15 = lane & 15, q = lane >> 4, q8 = q * 8, c0 = 4 * q;
  const int b = blockIdx.x;
  float* xbuf = ws + (size_t)b * SLAB;      // consumed by DOWN before R overwrites
  float* rl   = ws + (size_t)b * SLAB;
  float* du   = DU + (size_t)b * SLAB;

  // per-thread LDS read offsets (shorts): row (l15 + k), col i0, per kb
  int off_r[KBN];
#pragma unroll
  for (int kb = 0; kb < KBN; ++kb) {
    int s = kb * 32 + q8;
    int k = s / 48, i0 = s - 48 * k;
    off_r[kb] = (l15 + k) * RS + i0;
  }

  {
    short8 A[3][KBN];
    f32x4 bv[3];
    load_wA<3>(dw, db, A, bv, 0, l15, q8, c0);
    zero_carry(sb, tid);
    __syncthreads();
    const int rb16 = wid * 16, chb = c0;
    int p = 0;
    // ---------------- DOWN: d[h] = x[h] + convW(d[h-1]) ----------------
    initN<3>(sb, xbuf, (size_t)C_, du, rb16, chb, l15);
    for (int s = 1; s < H_; ++s) {
      stepN<3>(sb + (size_t)p * CBUF, sb + (size_t)(p ^ 1) * CBUF, A, bv, off_r,
               xbuf + (size_t)s * WC, (size_t)C_, du + (size_t)s * WC, rb16, chb, l15);
      p ^= 1;
    }
    // ---------------- UP (down weights; carry = D[63] persists) --------
    for (int s = 1; s < H_; ++s) {
      int ih = (s <= H_ - 2) ? (H_ - 2 - s) : (H_ - 1);
      stepN<3>(sb + (size_t)p * CBUF, sb + (size_t)(p ^ 1) * CBUF, A, bv, off_r,
               du + (size_t)ih * WC, (size_t)C_, du + (size_t)(H_ - 1 - s) * WC,
               rb16, chb, l15);
      p ^= 1;
    }
  }
  __syncthreads();   // U global stores drained before RIGHT reads them

  if (wid < 4) hseq<2>(sb, 0, rw, rb, lw, lb, du, rl, wid & 3, l15, q8, c0, off_r, tid);
  else         hseq<1>(sb, 2, rw, rb, lw, lb, du, rl, wid & 3, l15, q8, c0, off_r, tid);
}

// x [b][c][h][w] -> xT [b][h][w][c]
__global__ __launch_bounds__(256) void xpose_chw_hwc(const float* __restrict__ x,
                                                     float* __restrict__ xT) {
  __shared__ float t[C_ * 129];
  const int bh = blockIdx.x, b = bh >> 6, h = bh & 63;
  const float* src = x + (size_t)b * SLAB + (size_t)h * W_;
  float* dst = xT + (size_t)b * SLAB + (size_t)h * (W_ * C_);
  for (int i = threadIdx.x; i < C_ * W_; i += 256) {
    int c = i >> 7, w = i & 127;
    t[c * 129 + w] = src[(size_t)c * (H_ * W_) + w];
  }
  __syncthreads();
  for (int i = threadIdx.x; i < C_ * W_; i += 256) {
    int w = i / C_, c = i - w * C_;
    dst[i] = t[c * 129 + w];
  }
}

// L [b][w][h][c] -> out [b][c][h][w]
__global__ __launch_bounds__(256) void xpose_whc_chw(const float* __restrict__ L,
                                                     float* __restrict__ out) {
  __shared__ float t[W_ * 49];
  const int bh = blockIdx.x, b = bh >> 6, h = bh & 63;
  const float* src = L + (size_t)b * SLAB + (size_t)h * C_;
  float* dst = out + (size_t)b * SLAB + (size_t)h * W_;
  for (int i = threadIdx.x; i < W_ * C_; i += 256) {
    int w = i / C_, c = i - w * C_;
    t[w * 49 + c] = src[(size_t)w * (H_ * C_) + c];
  }
  __syncthreads();
  for (int i = threadIdx.x; i < C_ * W_; i += 256) {
    int c = i >> 7, w = i & 127;
    dst[(size_t)c * (H_ * W_) + w] = t[w * 49 + c];
  }
}

extern "C" void kernel_launch(void* const* d_in, const int* in_sizes, int n_in,
                              void* d_out, int out_size, void* d_ws, size_t ws_size,
                              hipStream_t stream) {
  const float* x  = (const float*)d_in[0];
  const float* dw = (const float*)d_in[1];
  const float* db = (const float*)d_in[2];
  const float* rw = (const float*)d_in[3];
  const float* rb = (const float*)d_in[4];
  const float* lw = (const float*)d_in[5];
  const float* lb = (const float*)d_in[6];
  float* DU = (float*)d_out;
  float* WS = (float*)d_ws;

  xpose_chw_hwc<<<B_ * H_, 256, 0, stream>>>(x, WS);
  scnn_mfma<<<B_, 512, 0, stream>>>(WS, dw, db, rw, rb, lw, lb, DU);
  xpose_whc_chw<<<B_ * H_, 256, 0, stream>>>(WS, DU);
}

// Round 7
// 408.812 us; speedup vs baseline: 2.5422x; 1.3690x over previous
//
#include <hip/hip_runtime.h>
#include <hip/hip_bf16.h>

#define B_ 32
#define C_ 48
#define H_ 64
#define W_ 128
#define K_ 5
#define SLAB (C_*H_*W_)
#define RS 56                 // carry row stride in bf16 (112 B, 16B-aligned)
#define ROWS 136              // 128 rows + top/bottom halo; rows >129 stay zero
#define CBUF (ROWS*RS)        // 7616 shorts per buffer (15232 B)
#define WC (W_*C_)
#define HC (H_*C_)
#define KBN 8                 // dense K' = 256: k' = k*48 + i, 240 real + 16 pad

typedef __attribute__((ext_vector_type(8))) short short8;
typedef __attribute__((ext_vector_type(4))) float f32x4;

__device__ __forceinline__ void lbar() {
  asm volatile("s_waitcnt lgkmcnt(0)\n\ts_barrier" ::: "memory");
}

__device__ __forceinline__ unsigned short f2bf(float f) {
  union { float f; unsigned u; } v; v.f = f;
  unsigned r = v.u + 0x7fffu + ((v.u >> 16) & 1u);
  return (unsigned short)(r >> 16);
}

__device__ __forceinline__ unsigned pk2(float a, float b) {
  union { __hip_bfloat162 h; unsigned u; } z;
  z.h = __float22bfloat162_rn(float2{a, b});
  return z.u;
}

// Weights as MFMA A operand, dense K': A[m][k'], m = mt*16 + l15,
// k' = kb*32 + q*8 + j -> k = k'/48, i = k'%48; k' >= 240 -> 0.
// (48 % 8 == 0: an aligned 8-block never crosses a tap boundary.)
__device__ __forceinline__ void load_wA(const float* __restrict__ wgt,
                                        const float* __restrict__ bias,
                                        short8 A[3][KBN], f32x4 bv[3],
                                        int l15, int q8, int c0) {
#pragma unroll
  for (int mt = 0; mt < 3; ++mt) {
#pragma unroll
    for (int r = 0; r < 4; ++r) bv[mt][r] = bias[mt * 16 + c0 + r];
#pragma unroll
    for (int kb = 0; kb < KBN; ++kb) {
      short8 f;
#pragma unroll
      for (int j = 0; j < 8; ++j) {
        int kp = kb * 32 + q8 + j;
        int k = kp / 48, i = kp - 48 * k;
        f[j] = (kp < 240)
             ? (short)f2bf(wgt[(mt * 16 + l15) * (C_ * K_) + i * K_ + k])
             : (short)0;
      }
      A[mt][kb] = f;
    }
  }
}

template<int NTW>
__device__ __forceinline__ void load_xin(float4 xv[NTW][3], const float* __restrict__ inp,
                                         size_t lRS, int n0, int l15, int c0) {
#pragma unroll
  for (int nt = 0; nt < NTW; ++nt) {
    const float* p = inp + (size_t)(n0 + nt * 16 + l15) * lRS + c0;
#pragma unroll
    for (int mt = 0; mt < 3; ++mt) xv[nt][mt] = *(const float4*)(p + mt * 16);
  }
}

// One step. SPL-way accumulator chain split (kb % SPL) keeps the MFMA pipe
// issue-bound instead of dependent-latency-bound.
template<int NTW, int SPL>
__device__ __forceinline__ void do_step(const unsigned short* __restrict__ scr,
                                        unsigned short* __restrict__ scw,
                                        const short8 A[3][KBN], const f32x4 bv[3],
                                        const float4 xv[NTW][3], const int off_r[KBN],
                                        float* __restrict__ outp,
                                        int n0, int l15, int c0) {
  f32x4 acc[SPL][NTW][3];
#pragma unroll
  for (int s = 0; s < SPL; ++s)
#pragma unroll
    for (int nt = 0; nt < NTW; ++nt)
#pragma unroll
      for (int mt = 0; mt < 3; ++mt)
        acc[s][nt][mt] = (s == 0) ? bv[mt] : (f32x4){0.f, 0.f, 0.f, 0.f};

#pragma unroll
  for (int kb = 0; kb < KBN; ++kb) {
    short8 pf[NTW];
#pragma unroll
    for (int nt = 0; nt < NTW; ++nt)
      pf[nt] = *(const short8*)(scr + (size_t)(n0 + nt * 16) * RS + off_r[kb]);
#pragma unroll
    for (int nt = 0; nt < NTW; ++nt)
#pragma unroll
      for (int mt = 0; mt < 3; ++mt)
        acc[kb % SPL][nt][mt] = __builtin_amdgcn_mfma_f32_16x16x32_bf16(
            A[mt][kb], pf[nt], acc[kb % SPL][nt][mt], 0, 0, 0);
  }

#pragma unroll
  for (int nt = 0; nt < NTW; ++nt) {
    const int row = n0 + nt * 16 + l15;
#pragma unroll
    for (int mt = 0; mt < 3; ++mt) {
      f32x4 a = acc[0][nt][mt];
#pragma unroll
      for (int s = 1; s < SPL; ++s)
#pragma unroll
        for (int r = 0; r < 4; ++r) a[r] += acc[s][nt][mt][r];
      float4 v;
      v.x = a[0] + xv[nt][mt].x; v.y = a[1] + xv[nt][mt].y;
      v.z = a[2] + xv[nt][mt].z; v.w = a[3] + xv[nt][mt].w;
      *(float4*)(outp + (size_t)row * C_ + mt * 16 + c0) = v;
      uint2 pk; pk.x = pk2(v.x, v.y); pk.y = pk2(v.z, v.w);
      *(uint2*)(scw + (size_t)(row + 2) * RS + mt * 16 + c0) = pk;
    }
  }
  lbar();
}

// Pass-initial: carry = inp, out = inp.
template<int NTW>
__device__ __forceinline__ void init_store(unsigned short* __restrict__ scw,
                                           const float* __restrict__ inp, size_t lRS,
                                           float* __restrict__ outp,
                                           int n0, int l15, int c0) {
  float4 xv[NTW][3];
  load_xin<NTW>(xv, inp, lRS, n0, l15, c0);
#pragma unroll
  for (int nt = 0; nt < NTW; ++nt) {
    const int row = n0 + nt * 16 + l15;
#pragma unroll
    for (int mt = 0; mt < 3; ++mt) {
      float4 v = xv[nt][mt];
      *(float4*)(outp + (size_t)row * C_ + mt * 16 + c0) = v;
      uint2 pk; pk.x = pk2(v.x, v.y); pk.y = pk2(v.z, v.w);
      *(uint2*)(scw + (size_t)(row + 2) * RS + mt * 16 + c0) = pk;
    }
  }
  lbar();
}

// Software-pipelined pass: prefetch inputs one step ahead; double-buffered carry.
template<int NTW, int SPL, class FIN, class FOUT>
__device__ __forceinline__ void run_pass(unsigned short* sb, int& p,
                                         const short8 A[3][KBN], const f32x4 bv[3],
                                         const int off_r[KBN],
                                         int nsteps, FIN inadr, size_t lRS, FOUT outadr,
                                         int n0, int l15, int c0) {
  float4 xa[NTW][3], xb[NTW][3];
  load_xin<NTW>(xa, inadr(1), lRS, n0, l15, c0);
  for (int s = 1; s <= nsteps; s += 2) {
    {
      int sn = (s + 1 <= nsteps) ? s + 1 : nsteps;
      load_xin<NTW>(xb, inadr(sn), lRS, n0, l15, c0);
      __builtin_amdgcn_sched_barrier(0x38F);
      do_step<NTW, SPL>(sb + (size_t)p * CBUF, sb + (size_t)(p ^ 1) * CBUF,
                        A, bv, xa, off_r, outadr(s), n0, l15, c0);
      p ^= 1;
    }
    if (s + 1 <= nsteps) {
      int sn = (s + 2 <= nsteps) ? s + 2 : nsteps;
      load_xin<NTW>(xa, inadr(sn), lRS, n0, l15, c0);
      __builtin_amdgcn_sched_barrier(0x38F);
      do_step<NTW, SPL>(sb + (size_t)p * CBUF, sb + (size_t)(p ^ 1) * CBUF,
                        A, bv, xb, off_r, outadr(s + 1), n0, l15, c0);
      p ^= 1;
    }
  }
}

// 4 waves (256 thr) per batch, grid 32. W passes: wave = 2 n-tiles; H: 1 n-tile.
__global__ __launch_bounds__(256, 1) void scnn_mfma(
    float* ws,                       // xT [b][h][w][c]; then R/L [b][t][h][c] (alias)
    const float* __restrict__ dw, const float* __restrict__ db,
    const float* __restrict__ rw, const float* __restrict__ rb,
    const float* __restrict__ lw, const float* __restrict__ lb,
    float* __restrict__ DU)          // d_out: D/U slabs [b][h][w][c]
{
  __shared__ unsigned short sb[2 * CBUF];   // 30464 B
  const int tid = threadIdx.x, lane = tid & 63, wid = tid >> 6;
  const int l15 = lane & 15, q = lane >> 4, q8 = q * 8, c0 = 4 * q;
  const int b = blockIdx.x;
  float* xbuf = ws + (size_t)b * SLAB;      // consumed by DOWN before R overwrites
  float* rl   = ws + (size_t)b * SLAB;
  float* du   = DU + (size_t)b * SLAB;
  const int n0w = wid * 32, n0h = wid * 16;

  // per-thread dense-K LDS read offsets (shorts): row (l15 + k), col i0
  int off_r[KBN];
#pragma unroll
  for (int kb = 0; kb < KBN; ++kb) {
    int s = kb * 32 + q8;
    int k = s / 48, i0 = s - 48 * k;
    off_r[kb] = (l15 + k) * RS + i0;
  }

  short8 A[3][KBN];
  f32x4 bv[3];
  int p = 0;

  // ---------------- DOWN: d[h] = x[h] + convW(d[h-1]) ----------------
  load_wA(dw, db, A, bv, l15, q8, c0);
  { unsigned* z = (unsigned*)sb; for (int i = tid; i < CBUF; i += 256) z[i] = 0u; }
  __syncthreads();
  init_store<2>(sb, xbuf, (size_t)C_, du, n0w, l15, c0);
  run_pass<2, 2>(sb, p, A, bv, off_r, H_ - 1,
                 [&](int s) { return xbuf + (size_t)s * WC; }, (size_t)C_,
                 [&](int s) { return du + (size_t)s * WC; }, n0w, l15, c0);
  __syncthreads();

  // ---------------- UP (down weights; carry = D[63] persists) --------
  run_pass<2, 2>(sb, p, A, bv, off_r, H_ - 1,
                 [&](int s) { int ih = (s <= H_ - 2) ? (H_ - 2 - s) : (H_ - 1);
                              return du + (size_t)ih * WC; }, (size_t)C_,
                 [&](int s) { return du + (size_t)(H_ - 1 - s) * WC; }, n0w, l15, c0);
  __syncthreads();

  // ---------------- RIGHT: r[t] = U[...,t] + convH(r[t-1]) -----------
  load_wA(rw, rb, A, bv, l15, q8, c0);
  { unsigned* z = (unsigned*)sb; for (int i = tid; i < CBUF; i += 256) z[i] = 0u; }
  __syncthreads();
  p = 0;
  init_store<1>(sb, du, (size_t)WC, rl, n0h, l15, c0);
  run_pass<1, 4>(sb, p, A, bv, off_r, W_ - 1,
                 [&](int s) { return du + (size_t)s * C_; }, (size_t)WC,
                 [&](int s) { return rl + (size_t)s * HC; }, n0h, l15, c0);
  __syncthreads();

  // ---------------- LEFT (carry = R[127]; L[127]=R[127] in place) ----
  load_wA(lw, lb, A, bv, l15, q8, c0);
  run_pass<1, 4>(sb, p, A, bv, off_r, W_ - 1,
                 [&](int s) { return rl + (size_t)(W_ - 1 - s) * HC; }, (size_t)C_,
                 [&](int s) { return rl + (size_t)(W_ - 1 - s) * HC; }, n0h, l15, c0);
}

// x [b][c][h][w] -> xT [b][h][w][c]
__global__ __launch_bounds__(256) void xpose_chw_hwc(const float* __restrict__ x,
                                                     float* __restrict__ xT) {
  __shared__ float t[C_ * 129];
  const int bh = blockIdx.x, b = bh >> 6, h = bh & 63;
  const float* src = x + (size_t)b * SLAB + (size_t)h * W_;
  float* dst = xT + (size_t)b * SLAB + (size_t)h * (W_ * C_);
  for (int i = threadIdx.x; i < C_ * W_; i += 256) {
    int c = i >> 7, w = i & 127;
    t[c * 129 + w] = src[(size_t)c * (H_ * W_) + w];
  }
  __syncthreads();
  for (int i = threadIdx.x; i < C_ * W_; i += 256) {
    int w = i / C_, c = i - w * C_;
    dst[i] = t[c * 129 + w];
  }
}

// L [b][w][h][c] -> out [b][c][h][w]
__global__ __launch_bounds__(256) void xpose_whc_chw(const float* __restrict__ L,
                                                     float* __restrict__ out) {
  __shared__ float t[W_ * 49];
  const int bh = blockIdx.x, b = bh >> 6, h = bh & 63;
  const float* src = L + (size_t)b * SLAB + (size_t)h * C_;
  float* dst = out + (size_t)b * SLAB + (size_t)h * W_;
  for (int i = threadIdx.x; i < W_ * C_; i += 256) {
    int w = i / C_, c = i - w * C_;
    t[w * 49 + c] = src[(size_t)w * (H_ * C_) + c];
  }
  __syncthreads();
  for (int i = threadIdx.x; i < C_ * W_; i += 256) {
    int c = i >> 7, w = i & 127;
    dst[(size_t)c * (H_ * W_) + w] = t[w * 49 + c];
  }
}

extern "C" void kernel_launch(void* const* d_in, const int* in_sizes, int n_in,
                              void* d_out, int out_size, void* d_ws, size_t ws_size,
                              hipStream_t stream) {
  const float* x  = (const float*)d_in[0];
  const float* dw = (const float*)d_in[1];
  const float* db = (const float*)d_in[2];
  const float* rw = (const float*)d_in[3];
  const float* rb = (const float*)d_in[4];
  const float* lw = (const float*)d_in[5];
  const float* lb = (const float*)d_in[6];
  float* DU = (float*)d_out;
  float* WS = (float*)d_ws;

  xpose_chw_hwc<<<B_ * H_, 256, 0, stream>>>(x, WS);
  scnn_mfma<<<B_, 256, 0, stream>>>(WS, dw, db, rw, rb, lw, lb, DU);
  xpose_whc_chw<<<B_ * H_, 256, 0, stream>>>(WS, DU);
}